// Round 17
// baseline (622.919 us; speedup 1.0000x reference)
//
#include <hip/hip_runtime.h>

#define N_NODES 100000
#define E_EDGES 3200000
#define F_IN    1433
#define K_PAD   1472   // w1t padded K (23*64)
#define NCH     98     // scan chunks of 1024
#define KPH     64     // k per phase; 23 phases (22 DMA + reg-staged tail)

typedef _Float16 f16x4 __attribute__((ext_vector_type(4)));
typedef _Float16 f16x8 __attribute__((ext_vector_type(8)));
typedef float    f32x4 __attribute__((ext_vector_type(4)));

__device__ __forceinline__ void gload_lds16(const void* g, void* l) {
    __builtin_amdgcn_global_load_lds(
        (const __attribute__((address_space(1))) unsigned int*)g,
        (__attribute__((address_space(3))) unsigned int*)l, 16, 0, 0);
}

// ---------------- init: counts=0 + W1^T fp16 [64][K_PAD] zero-padded ----------------
__global__ void k_init(const float* __restrict__ w1, _Float16* __restrict__ w1t,
                       int* __restrict__ counts) {
    int i = blockIdx.x * 256 + threadIdx.x;
    if (i < N_NODES) counts[i] = 0;
    if (i < 64 * K_PAD) {
        int n = i / K_PAD, k = i - n * K_PAD;
        float v = (k < F_IN) ? w1[(size_t)k * 64 + n] : 0.f;
        w1t[i] = (_Float16)v;
    }
}

__global__ void k_hist(const int* __restrict__ dst, int* __restrict__ counts) {
    int idx = blockIdx.x * 256 + threadIdx.x;      // 3125*256*4 = 3.2M
    int4 d4 = ((const int4*)dst)[idx];
    atomicAdd(&counts[d4.x], 1);
    atomicAdd(&counts[d4.y], 1);
    atomicAdd(&counts[d4.z], 1);
    atomicAdd(&counts[d4.w], 1);
}

// ---------------- exclusive scan of counts (chunked) ----------------
__global__ void k_scan_a(const int* __restrict__ counts, int* __restrict__ csum) {
    __shared__ int sh[256];
    int b = blockIdx.x, t = threadIdx.x;
    int s = 0;
    for (int j = 0; j < 4; ++j) {
        int idx = b * 1024 + j * 256 + t;
        if (idx < N_NODES) s += counts[idx];
    }
    sh[t] = s; __syncthreads();
    for (int off = 128; off > 0; off >>= 1) {
        if (t < off) sh[t] += sh[t + off];
        __syncthreads();
    }
    if (t == 0) csum[b] = sh[0];
}

__global__ void k_scan_b(int* __restrict__ csum) {
    __shared__ int sh[128];
    int t = threadIdx.x;
    int v = (t < NCH) ? csum[t] : 0;
    sh[t] = v; __syncthreads();
    for (int off = 1; off < 128; off <<= 1) {
        int u = (t >= off) ? sh[t - off] : 0;
        __syncthreads();
        sh[t] += u;
        __syncthreads();
    }
    if (t < NCH) csum[t] = sh[t] - v;   // exclusive
}

__global__ void k_scan_c(const int* __restrict__ counts, const int* __restrict__ csum,
                         int* __restrict__ offsets, int* __restrict__ cursor) {
    __shared__ int sh[256];
    int b = blockIdx.x, t = threadIdx.x;
    int base = b * 1024 + t * 4;
    int c0 = (base + 0 < N_NODES) ? counts[base + 0] : 0;
    int c1 = (base + 1 < N_NODES) ? counts[base + 1] : 0;
    int c2 = (base + 2 < N_NODES) ? counts[base + 2] : 0;
    int c3 = (base + 3 < N_NODES) ? counts[base + 3] : 0;
    int tot = c0 + c1 + c2 + c3;
    sh[t] = tot; __syncthreads();
    for (int off = 1; off < 256; off <<= 1) {
        int v = (t >= off) ? sh[t - off] : 0;
        __syncthreads();
        sh[t] += v;
        __syncthreads();
    }
    int excl = sh[t] - tot;
    int o = csum[b] + excl;
    if (base + 0 < N_NODES) { offsets[base + 0] = o;            cursor[base + 0] = o; }
    if (base + 1 < N_NODES) { int q = o + c0;      offsets[base + 1] = q; cursor[base + 1] = q; }
    if (base + 2 < N_NODES) { int q = o + c0 + c1; offsets[base + 2] = q; cursor[base + 2] = q; }
    if (base + 3 < N_NODES) { int q = o + c0 + c1 + c2; offsets[base + 3] = q; cursor[base + 3] = q; }
}

// ---------------- scatter (standalone, sweep-localized writes) ----------------
__global__ void k_scatter(const int* __restrict__ src, const int* __restrict__ dst,
                          int* __restrict__ cursor, int* __restrict__ sorted_src) {
    const int tid = threadIdx.x;
    const int sid = blockIdx.x;                   // 1563 blocks x 2048 edges
    for (int sweep = 0; sweep < 7; ++sweep) {     // dst>>14: 0..6 for dst<100000
        #pragma unroll
        for (int rep = 0; rep < 2; ++rep) {
            int i4 = sid * 512 + rep * 256 + tid;
            if (i4 < E_EDGES / 4) {
                int4 s4 = ((const int4*)src)[i4];
                int4 d4 = ((const int4*)dst)[i4];
                int p;
                if ((d4.x >> 14) == sweep) { p = atomicAdd(&cursor[d4.x], 1); sorted_src[p] = s4.x; }
                if ((d4.y >> 14) == sweep) { p = atomicAdd(&cursor[d4.y], 1); sorted_src[p] = s4.y; }
                if ((d4.z >> 14) == sweep) { p = atomicAdd(&cursor[d4.z], 1); sorted_src[p] = s4.z; }
                if ((d4.w >> 14) == sweep) { p = atomicAdd(&cursor[d4.w], 1); sorted_src[p] = s4.w; }
            }
        }
    }
}

// ---------------- GEMM1 + fused att1: BARRIER-FREE single-wave blocks ----------------
// One wave per block owns 32 rows x 64 cols. All DMA destinations and LDS reads
// are wave-private -> NO s_barrier anywhere; the wave free-runs on counted vmcnt
// (16 DMA instr/phase, 2-deep double buffer => steady-state vmcnt(16)).
// 3125 blocks x 32 rows = 100000 exact (no row guards). 32 KB LDS -> 5 blocks/CU.
__global__ __launch_bounds__(64) void k_gemm1(const float* __restrict__ x,
                                              const _Float16* __restrict__ w1t,
                                              const float* __restrict__ att_src1,
                                              const float* __restrict__ att_dst1,
                                              _Float16* __restrict__ h1,
                                              float* __restrict__ a_s1,
                                              float* __restrict__ a_d1) {
    __shared__ __align__(16) char AsB[2][32 * 256];   // 8 KB per buffer (fp32)
    __shared__ __align__(16) char BsB[2][64 * 128];   // 8 KB per buffer (fp16)
    const int lane = threadIdx.x & 63;
    const int l16  = lane & 15;
    const int l4   = lane >> 4;
    const int brow0 = blockIdx.x * 32;

    f32x4 acc[2][4] = {};

    // stage A: 32 rows x 64 fp32 = 8 instr x 1KB; slot q holds global chunk q^(row&7)
    auto stageA = [&](int buf, int ph) {
        #pragma unroll
        for (int j = 0; j < 8; ++j) {
            int p = j * 64 + lane;
            int row = p >> 4, q = p & 15;
            int qs = q ^ (row & 7);
            const float* gp = x + (size_t)(brow0 + row) * F_IN + ph * KPH + qs * 4;
            gload_lds16(gp, AsB[buf] + j * 1024);
        }
    };
    // stage B: 64 cols x 64 fp16 = 8 instr x 1KB; slot c holds global chunk c^(col&7)
    auto stageB = [&](int buf, int ph) {
        #pragma unroll
        for (int j = 0; j < 8; ++j) {
            int p = j * 64 + lane;
            int col = p >> 3, c = p & 7;
            int cs = c ^ (col & 7);
            const _Float16* gp = w1t + (size_t)col * K_PAD + ph * KPH + cs * 8;
            gload_lds16(gp, BsB[buf] + j * 1024);
        }
    };
    // tail phase 22 (k 1408..1471): reg-staged, zero-fill k>=1433
    auto stageTailA = [&](int buf) {
        #pragma unroll
        for (int j = 0; j < 8; ++j) {
            int p = j * 64 + lane;
            int row = p >> 4, q = p & 15;
            int qs = q ^ (row & 7);
            const float* gp = x + (size_t)(brow0 + row) * F_IN;
            float4 v;
            #pragma unroll
            for (int jj = 0; jj < 4; ++jj) {
                int k = 1408 + qs * 4 + jj;
                ((float*)&v)[jj] = (k < F_IN) ? gp[k] : 0.f;
            }
            *(float4*)(AsB[buf] + row * 256 + q * 16) = v;
        }
    };
    auto compute = [&](int buf) {
        #pragma unroll
        for (int st = 0; st < 4; ++st) {
            #pragma unroll
            for (int rt = 0; rt < 2; ++rt) {
                const int rA = rt * 16 + l16;
                float4 af = *(const float4*)(AsB[buf] + rA * 256
                                             + ((((st << 2) + l4) ^ (rA & 7)) << 4));
                f16x4 a = { (_Float16)af.x, (_Float16)af.y, (_Float16)af.z, (_Float16)af.w };
                #pragma unroll
                for (int t = 0; t < 4; ++t) {
                    const int cB = t * 16 + l16;
                    const int chunk = (st << 1) + (l4 >> 1);
                    const int boff = cB * 128 + ((chunk ^ (cB & 7)) << 4) + ((l4 & 1) << 3);
                    f16x4 b = *(const f16x4*)(BsB[buf] + boff);
                    acc[rt][t] = __builtin_amdgcn_mfma_f32_16x16x16f16(a, b, acc[rt][t], 0, 0, 0);
                }
            }
        }
    };

    // prologue: phases 0,1 in flight (32 DMA instructions)
    stageA(0, 0); stageB(0, 0);
    stageA(1, 1); stageB(1, 1);
    for (int ph = 0; ph <= 19; ++ph) {
        asm volatile("s_waitcnt vmcnt(16)" ::: "memory");   // phase ph's 16 DMAs done
        __builtin_amdgcn_sched_barrier(0);
        compute(ph & 1);
        asm volatile("s_waitcnt lgkmcnt(0)" ::: "memory");  // LDS reads retired
        __builtin_amdgcn_sched_barrier(0);
        stageA(ph & 1, ph + 2); stageB(ph & 1, ph + 2);
    }
    // ph=20: stage 22 = B via DMA + A via reg path
    asm volatile("s_waitcnt vmcnt(16)" ::: "memory");
    __builtin_amdgcn_sched_barrier(0);
    compute(0);
    asm volatile("s_waitcnt lgkmcnt(0)" ::: "memory");
    __builtin_amdgcn_sched_barrier(0);
    stageB(0, 22);
    stageTailA(0);          // reg loads drain vmcnt conservatively - safe
    // ph=21
    asm volatile("s_waitcnt vmcnt(8)" ::: "memory");
    __builtin_amdgcn_sched_barrier(0);
    compute(1);
    // ph=22
    asm volatile("s_waitcnt vmcnt(0) lgkmcnt(0)" ::: "memory");
    __builtin_amdgcn_sched_barrier(0);
    compute(0);

    // epilogue: h1 write + fused attention coefficients (reduce over 8 channels)
    #pragma unroll
    for (int rt = 0; rt < 2; ++rt) {
        const int wrow0 = brow0 + rt * 16;
        #pragma unroll
        for (int t = 0; t < 4; ++t) {
            const int head = t * 2 + (l16 >> 3);
            const int ch   = l16 & 7;
            const float asc = att_src1[head * 8 + ch];
            const float adc = att_dst1[head * 8 + ch];
            #pragma unroll
            for (int j = 0; j < 4; ++j) {
                int r = wrow0 + l4 * 4 + j;   // C: col = lane&15, row = (lane>>4)*4 + reg
                float ps = acc[rt][t][j] * asc, pd = acc[rt][t][j] * adc;
                ps += __shfl_xor(ps, 1); ps += __shfl_xor(ps, 2); ps += __shfl_xor(ps, 4);
                pd += __shfl_xor(pd, 1); pd += __shfl_xor(pd, 2); pd += __shfl_xor(pd, 4);
                h1[(size_t)r * 64 + t * 16 + l16] = (_Float16)acc[rt][t][j];
                if (ch == 0) {
                    a_s1[r * 8 + head] = ps;
                    a_d1[r * 8 + head] = pd;
                }
            }
        }
    }
}

// ---------------- layer-1 aggregate (defer-max, 8-deep gather batching) ----------------
__global__ __launch_bounds__(256) void k_agg1(
    const int* __restrict__ offsets, const int* __restrict__ counts,
    const int* __restrict__ sorted_src,
    const float* __restrict__ a_s1, const float* __restrict__ a_d1,
    const _Float16* __restrict__ h1, const float* __restrict__ b1,
    const float* __restrict__ w2, const float* __restrict__ att_src2,
    const float* __restrict__ att_dst2,
    _Float16* __restrict__ g, float* __restrict__ a_s2, float* __restrict__ a_d2) {
    const int lane = threadIdx.x & 63;
    const int wave = threadIdx.x >> 6;
    const int h    = lane & 7;
    const int es   = lane >> 3;
    const int n    = blockIdx.x * 4 + wave;     // 25000*4 = 100000 exact
    const int start = offsets[n];
    const int cnt   = counts[n];
    const float adn = a_d1[n * 8 + h];
    float et = a_s1[n * 8 + h] + adn;
    const float e_self = et > 0.f ? et : 0.2f * et;

    float m = e_self, denom = 0.f;
    float acc[8] = {0.f,0.f,0.f,0.f,0.f,0.f,0.f,0.f};
    if (es == 0) {                 // self-loop: exp(e_self - m) = 1
        denom = 1.f;
        f16x8 hv0 = *(const f16x8*)(h1 + (size_t)n * 64 + h * 8);
        #pragma unroll
        for (int c = 0; c < 8; ++c) acc[c] = (float)hv0[c];
    }
    for (int i = es; i < cnt; i += 64) {
        int   sx[8];
        float ax[8];
        f16x8 vx[8];
        bool  bx[8];
        #pragma unroll
        for (int u = 0; u < 8; ++u) {
            int iu = i + u * 8;
            bx[u] = iu < cnt;
            sx[u] = sorted_src[start + (bx[u] ? iu : i)];
        }
        #pragma unroll
        for (int u = 0; u < 8; ++u) ax[u] = a_s1[sx[u] * 8 + h];
        #pragma unroll
        for (int u = 0; u < 8; ++u) vx[u] = *(const f16x8*)(h1 + (size_t)sx[u] * 64 + h * 8);
        #pragma unroll
        for (int u = 0; u < 8; ++u) {
            if (bx[u]) {
                float e = ax[u] + adn; e = e > 0.f ? e : 0.2f * e;
                if (e > m + 8.f) {     // rare rescale
                    float sc = __expf(m - e); denom *= sc;
                    #pragma unroll
                    for (int c = 0; c < 8; ++c) acc[c] *= sc;
                    m = e;
                }
                float p = __expf(e - m); denom += p;
                #pragma unroll
                for (int c = 0; c < 8; ++c) acc[c] += p * (float)vx[u][c];
            }
        }
    }
    // combine 8 edge-slots per head (xor 8,16,32); m may differ after rescales
    #pragma unroll
    for (int d = 8; d < 64; d <<= 1) {
        float mo = __shfl_xor(m, d);
        float dn = __shfl_xor(denom, d);
        float mn = fmaxf(m, mo);
        float sa = __expf(m - mn), sb = __expf(mo - mn);
        denom = denom * sa + dn * sb;
        #pragma unroll
        for (int c = 0; c < 8; ++c) {
            float ao = __shfl_xor(acc[c], d);
            acc[c] = acc[c] * sa + ao * sb;
        }
        m = mn;
    }
    float inv = 1.f / (denom + 1e-16f);
    float hc[8];
    #pragma unroll
    for (int c = 0; c < 8; ++c) {
        float v = acc[c] * inv;
        v += __shfl_xor(v, 1);
        v += __shfl_xor(v, 2);
        v += __shfl_xor(v, 4);                  // mean over heads
        float o = 0.125f * v + b1[c];
        hc[c] = o > 0.f ? o : expm1f(o);        // ELU
    }
    if (lane == 0) {
        float s2 = 0.f, d2 = 0.f;
        f16x8 gr;
        #pragma unroll
        for (int j = 0; j < 7; ++j) {
            float t = 0.f;
            #pragma unroll
            for (int c = 0; c < 8; ++c) t += hc[c] * w2[c * 7 + j];
            gr[j] = (_Float16)t;
            s2 += t * att_src2[j];
            d2 += t * att_dst2[j];
        }
        gr[7] = (_Float16)0.f;
        *(f16x8*)(g + (size_t)n * 8) = gr;
        a_s2[n] = s2;
        a_d2[n] = d2;
    }
}

// ---------------- layer-2 aggregate (defer-max, 8-deep batching) + log_softmax ----------------
__global__ __launch_bounds__(256) void k_agg2(
    const int* __restrict__ offsets, const int* __restrict__ counts,
    const int* __restrict__ sorted_src,
    const float* __restrict__ a_s2, const float* __restrict__ a_d2,
    const _Float16* __restrict__ g, const float* __restrict__ b2,
    float* __restrict__ outp) {
    const int tid  = threadIdx.x;
    const int lane = tid & 63;
    const int wave = tid >> 6;
    const int grp  = lane >> 3;
    const int s    = lane & 7;
    const int n    = blockIdx.x * 32 + wave * 8 + grp;
    const int start = offsets[n];
    const int cnt   = counts[n];
    const float adn = a_d2[n];
    float et = a_s2[n] + adn;
    const float e_self = et > 0.f ? et : 0.2f * et;

    float m = e_self, denom = 0.f;
    float acc[8] = {0.f,0.f,0.f,0.f,0.f,0.f,0.f,0.f};
    if (s == 0) {
        denom = 1.f;
        f16x8 gv0 = *(const f16x8*)(g + (size_t)n * 8);
        #pragma unroll
        for (int c = 0; c < 8; ++c) acc[c] = (float)gv0[c];
    }
    for (int i = s; i < cnt; i += 64) {
        int   sx[8];
        float ax[8];
        f16x8 vx[8];
        bool  bx[8];
        #pragma unroll
        for (int u = 0; u < 8; ++u) {
            int iu = i + u * 8;
            bx[u] = iu < cnt;
            sx[u] = sorted_src[start + (bx[u] ? iu : i)];
        }
        #pragma unroll
        for (int u = 0; u < 8; ++u) ax[u] = a_s2[sx[u]];
        #pragma unroll
        for (int u = 0; u < 8; ++u) vx[u] = *(const f16x8*)(g + (size_t)sx[u] * 8);
        #pragma unroll
        for (int u = 0; u < 8; ++u) {
            if (bx[u]) {
                float e = ax[u] + adn; e = e > 0.f ? e : 0.2f * e;
                if (e > m + 8.f) {
                    float sc = __expf(m - e); denom *= sc;
                    #pragma unroll
                    for (int c = 0; c < 8; ++c) acc[c] *= sc;
                    m = e;
                }
                float p = __expf(e - m); denom += p;
                #pragma unroll
                for (int c = 0; c < 8; ++c) acc[c] += p * (float)vx[u][c];
            }
        }
    }
    #pragma unroll
    for (int d = 1; d < 8; d <<= 1) {
        float mo = __shfl_xor(m, d, 8);
        float dn = __shfl_xor(denom, d, 8);
        float mn = fmaxf(m, mo);
        float sa = __expf(m - mn), sb = __expf(mo - mn);
        denom = denom * sa + dn * sb;
        #pragma unroll
        for (int c = 0; c < 8; ++c) {
            float ao = __shfl_xor(acc[c], d, 8);
            acc[c] = acc[c] * sa + ao * sb;
        }
        m = mn;
    }
    float inv = 1.f / (denom + 1e-16f);
    float o[7]; float mx = -1e30f;
    #pragma unroll
    for (int c = 0; c < 7; ++c) { o[c] = acc[c] * inv + b2[c]; mx = fmaxf(mx, o[c]); }
    float se = 0.f;
    #pragma unroll
    for (int c = 0; c < 7; ++c) se += __expf(o[c] - mx);
    float ls = mx + logf(se);
    if (s < 7) outp[n * 7 + s] = o[s] - ls;
}

extern "C" void kernel_launch(void* const* d_in, const int* in_sizes, int n_in,
                              void* d_out, int out_size, void* d_ws, size_t ws_size,
                              hipStream_t stream) {
    const float* x        = (const float*)d_in[0];
    const int*   ei       = (const int*)d_in[1];
    const float* W1       = (const float*)d_in[2];
    const float* att_src1 = (const float*)d_in[3];
    const float* att_dst1 = (const float*)d_in[4];
    const float* b1       = (const float*)d_in[5];
    const float* W2       = (const float*)d_in[6];
    const float* att_src2 = (const float*)d_in[7];
    const float* att_dst2 = (const float*)d_in[8];
    const float* b2       = (const float*)d_in[9];
    const int* src = ei;
    const int* dst = ei + E_EDGES;

    char* ws = (char*)d_ws;
    size_t off = 0;
    auto alloc = [&](size_t bytes) -> char* {
        char* p = ws + off;
        off = (off + bytes + 255) & ~(size_t)255;
        return p;
    };
    _Float16* h1         = (_Float16*)alloc((size_t)N_NODES * 64 * 2);
    float*    a_s1       = (float*)   alloc((size_t)N_NODES * 8 * 4);
    float*    a_d1       = (float*)   alloc((size_t)N_NODES * 8 * 4);
    _Float16* w1t        = (_Float16*)alloc((size_t)64 * K_PAD * 2);
    int*      counts     = (int*)     alloc((size_t)N_NODES * 4);
    int*      offsets    = (int*)     alloc((size_t)N_NODES * 4);
    int*      cursor     = (int*)     alloc((size_t)N_NODES * 4);
    int*      csum       = (int*)     alloc((size_t)NCH * 4);
    int*      sorted_src = (int*)     alloc((size_t)(E_EDGES + 32) * 4);
    _Float16* gbuf       = (_Float16*)alloc((size_t)N_NODES * 8 * 2);
    float*    a_s2       = (float*)   alloc((size_t)N_NODES * 4);
    float*    a_d2       = (float*)   alloc((size_t)N_NODES * 4);
    float*    outp       = (float*)d_out;

    hipLaunchKernelGGL(k_init,    dim3(391),   dim3(256), 0, stream, W1, w1t, counts);
    hipLaunchKernelGGL(k_hist,    dim3(3125),  dim3(256), 0, stream, dst, counts);
    hipLaunchKernelGGL(k_scan_a,  dim3(NCH),   dim3(256), 0, stream, counts, csum);
    hipLaunchKernelGGL(k_scan_b,  dim3(1),     dim3(128), 0, stream, csum);
    hipLaunchKernelGGL(k_scan_c,  dim3(NCH),   dim3(256), 0, stream, counts, csum, offsets, cursor);
    hipLaunchKernelGGL(k_scatter, dim3(1563),  dim3(256), 0, stream, src, dst, cursor, sorted_src);
    hipLaunchKernelGGL(k_gemm1,   dim3(3125),  dim3(64),  0, stream, x, w1t, att_src1, att_dst1,
                       h1, a_s1, a_d1);
    hipLaunchKernelGGL(k_agg1,    dim3(25000), dim3(256), 0, stream, offsets, counts, sorted_src,
                       a_s1, a_d1, h1, b1, W2, att_src2, att_dst2, gbuf, a_s2, a_d2);
    hipLaunchKernelGGL(k_agg2,    dim3(3125),  dim3(256), 0, stream, offsets, counts, sorted_src,
                       a_s2, a_d2, gbuf, b2, outp);
}

// Round 18
// 594.653 us; speedup vs baseline: 1.0475x; 1.0475x over previous
//
#include <hip/hip_runtime.h>

#define N_NODES 100000
#define E_EDGES 3200000
#define F_IN    1433
#define K_PAD   1472   // w1t padded K (23*64)
#define NCH     98     // scan chunks of 1024
#define KPH     64     // k per phase; 22 DMA phases + guarded tail

typedef _Float16 f16x4 __attribute__((ext_vector_type(4)));
typedef _Float16 f16x8 __attribute__((ext_vector_type(8)));
typedef float    f32x4 __attribute__((ext_vector_type(4)));

__device__ __forceinline__ void gload_lds16(const void* g, void* l) {
    __builtin_amdgcn_global_load_lds(
        (const __attribute__((address_space(1))) unsigned int*)g,
        (__attribute__((address_space(3))) unsigned int*)l, 16, 0, 0);
}

// ---------------- init: counts=0 + W1^T fp16 [64][K_PAD] zero-padded ----------------
__global__ void k_init(const float* __restrict__ w1, _Float16* __restrict__ w1t,
                       int* __restrict__ counts) {
    int i = blockIdx.x * 256 + threadIdx.x;
    if (i < N_NODES) counts[i] = 0;
    if (i < 64 * K_PAD) {
        int n = i / K_PAD, k = i - n * K_PAD;
        float v = (k < F_IN) ? w1[(size_t)k * 64 + n] : 0.f;
        w1t[i] = (_Float16)v;
    }
}

__global__ void k_hist(const int* __restrict__ dst, int* __restrict__ counts) {
    int idx = blockIdx.x * 256 + threadIdx.x;      // 3125*256*4 = 3.2M
    int4 d4 = ((const int4*)dst)[idx];
    atomicAdd(&counts[d4.x], 1);
    atomicAdd(&counts[d4.y], 1);
    atomicAdd(&counts[d4.z], 1);
    atomicAdd(&counts[d4.w], 1);
}

// ---------------- exclusive scan of counts (chunked) ----------------
__global__ void k_scan_a(const int* __restrict__ counts, int* __restrict__ csum) {
    __shared__ int sh[256];
    int b = blockIdx.x, t = threadIdx.x;
    int s = 0;
    for (int j = 0; j < 4; ++j) {
        int idx = b * 1024 + j * 256 + t;
        if (idx < N_NODES) s += counts[idx];
    }
    sh[t] = s; __syncthreads();
    for (int off = 128; off > 0; off >>= 1) {
        if (t < off) sh[t] += sh[t + off];
        __syncthreads();
    }
    if (t == 0) csum[b] = sh[0];
}

__global__ void k_scan_b(int* __restrict__ csum) {
    __shared__ int sh[128];
    int t = threadIdx.x;
    int v = (t < NCH) ? csum[t] : 0;
    sh[t] = v; __syncthreads();
    for (int off = 1; off < 128; off <<= 1) {
        int u = (t >= off) ? sh[t - off] : 0;
        __syncthreads();
        sh[t] += u;
        __syncthreads();
    }
    if (t < NCH) csum[t] = sh[t] - v;   // exclusive
}

__global__ void k_scan_c(const int* __restrict__ counts, const int* __restrict__ csum,
                         int* __restrict__ offsets, int* __restrict__ cursor) {
    __shared__ int sh[256];
    int b = blockIdx.x, t = threadIdx.x;
    int base = b * 1024 + t * 4;
    int c0 = (base + 0 < N_NODES) ? counts[base + 0] : 0;
    int c1 = (base + 1 < N_NODES) ? counts[base + 1] : 0;
    int c2 = (base + 2 < N_NODES) ? counts[base + 2] : 0;
    int c3 = (base + 3 < N_NODES) ? counts[base + 3] : 0;
    int tot = c0 + c1 + c2 + c3;
    sh[t] = tot; __syncthreads();
    for (int off = 1; off < 256; off <<= 1) {
        int v = (t >= off) ? sh[t - off] : 0;
        __syncthreads();
        sh[t] += v;
        __syncthreads();
    }
    int excl = sh[t] - tot;
    int o = csum[b] + excl;
    if (base + 0 < N_NODES) { offsets[base + 0] = o;            cursor[base + 0] = o; }
    if (base + 1 < N_NODES) { int q = o + c0;      offsets[base + 1] = q; cursor[base + 1] = q; }
    if (base + 2 < N_NODES) { int q = o + c0 + c1; offsets[base + 2] = q; cursor[base + 2] = q; }
    if (base + 3 < N_NODES) { int q = o + c0 + c1 + c2; offsets[base + 3] = q; cursor[base + 3] = q; }
}

// ---------------- scatter (standalone, sweep-localized writes; r14 role verbatim) ----------------
__global__ void k_scatter(const int* __restrict__ src, const int* __restrict__ dst,
                          int* __restrict__ cursor, int* __restrict__ sorted_src) {
    const int tid = threadIdx.x;
    const int sid = blockIdx.x;                   // 1563 blocks x 2048 edges
    for (int sweep = 0; sweep < 7; ++sweep) {     // dst>>14: 0..6 for dst<100000
        #pragma unroll
        for (int rep = 0; rep < 2; ++rep) {
            int i4 = sid * 512 + rep * 256 + tid;
            if (i4 < E_EDGES / 4) {
                int4 s4 = ((const int4*)src)[i4];
                int4 d4 = ((const int4*)dst)[i4];
                int p;
                if ((d4.x >> 14) == sweep) { p = atomicAdd(&cursor[d4.x], 1); sorted_src[p] = s4.x; }
                if ((d4.y >> 14) == sweep) { p = atomicAdd(&cursor[d4.y], 1); sorted_src[p] = s4.y; }
                if ((d4.z >> 14) == sweep) { p = atomicAdd(&cursor[d4.z], 1); sorted_src[p] = s4.z; }
                if ((d4.w >> 14) == sweep) { p = atomicAdd(&cursor[d4.w], 1); sorted_src[p] = s4.w; }
            }
        }
    }
}

// ---------------- GEMM1 + fused att1 (r14 gemm role verbatim, standalone) ----------------
// 4-wave blocks, 2-deep counted-vmcnt global_load_lds pipeline. Full 3 blocks/CU
// with no scatter-role LDS competition (the fusion A/B this round tests).
__global__ __launch_bounds__(256) void k_gemm1(const float* __restrict__ x,
                                               const _Float16* __restrict__ w1t,
                                               const float* __restrict__ att_src1,
                                               const float* __restrict__ att_dst1,
                                               _Float16* __restrict__ h1,
                                               float* __restrict__ a_s1,
                                               float* __restrict__ a_d1) {
    __shared__ __align__(16) char AsB[2][64 * 256];   // 16 KB per buffer (fp32)
    __shared__ __align__(16) char BsB[2][64 * 128];   //  8 KB per buffer (fp16)
    const int tid  = threadIdx.x;
    const int lane = tid & 63;
    const int wave = tid >> 6;
    const int l16  = lane & 15;
    const int l4   = lane >> 4;
    const int brow0 = blockIdx.x * 64;

    f32x4 acc[4] = {};

    auto stageA = [&](int buf, int ph) {
        #pragma unroll
        for (int j = 0; j < 4; ++j) {
            int p = j * 256 + tid;
            int row = p >> 4, q = p & 15;
            int qs = q ^ (row & 7);
            int grow = brow0 + row; if (grow > N_NODES - 1) grow = N_NODES - 1;
            const float* gp = x + (size_t)grow * F_IN + ph * KPH + qs * 4;
            gload_lds16(gp, AsB[buf] + j * 4096 + wave * 1024);
        }
    };
    auto stageB = [&](int buf, int ph) {
        #pragma unroll
        for (int j = 0; j < 2; ++j) {
            int p = j * 256 + tid;
            int col = p >> 3, c = p & 7;
            int cs = c ^ (col & 7);
            const _Float16* gp = w1t + (size_t)col * K_PAD + ph * KPH + cs * 8;
            gload_lds16(gp, BsB[buf] + j * 4096 + wave * 1024);
        }
    };
    auto stageTailA = [&](int buf) {        // k 1408..1471, zero-fill k>=1433
        for (int i = tid; i < 1024; i += 256) {
            int row = i >> 4, q = i & 15;
            int qs = q ^ (row & 7);
            int grow = brow0 + row; if (grow > N_NODES - 1) grow = N_NODES - 1;
            const float* gp = x + (size_t)grow * F_IN;
            float4 v;
            #pragma unroll
            for (int jj = 0; jj < 4; ++jj) {
                int k = 1408 + qs * 4 + jj;
                ((float*)&v)[jj] = (k < F_IN) ? gp[k] : 0.f;
            }
            *(float4*)(AsB[buf] + row * 256 + q * 16) = v;
        }
    };
    auto compute = [&](int buf) {
        const int rA = wave * 16 + l16;
        const char* Ab = AsB[buf] + rA * 256;
        const int r7 = rA & 7;
        #pragma unroll
        for (int st = 0; st < 4; ++st) {
            float4 af = *(const float4*)(Ab + ((((st << 2) + l4) ^ r7) << 4));
            f16x4 a = { (_Float16)af.x, (_Float16)af.y, (_Float16)af.z, (_Float16)af.w };
            #pragma unroll
            for (int t = 0; t < 4; ++t) {
                const int cB = t * 16 + l16;
                const int chunk = (st << 1) + (l4 >> 1);
                const int boff = cB * 128 + ((chunk ^ (cB & 7)) << 4) + ((l4 & 1) << 3);
                f16x4 b = *(const f16x4*)(BsB[buf] + boff);
                acc[t] = __builtin_amdgcn_mfma_f32_16x16x16f16(a, b, acc[t], 0, 0, 0);
            }
        }
    };

    // prologue: stage phases 0 and 1 (12 DMAs in flight per wave)
    stageA(0, 0); stageB(0, 0);
    stageA(1, 1); stageB(1, 1);
    // steady state: compute(ph) from buf[ph&1]; stage(ph+2) into the freed buffer
    for (int ph = 0; ph <= 20; ++ph) {
        asm volatile("s_waitcnt vmcnt(6)" ::: "memory");   // buf[ph&1]'s 6 DMAs done
        __builtin_amdgcn_sched_barrier(0);
        __builtin_amdgcn_s_barrier();                      // all waves agree
        compute(ph & 1);
        asm volatile("s_waitcnt lgkmcnt(0)" ::: "memory"); // reads retired before overwrite
        __builtin_amdgcn_s_barrier();
        int nxt = ph + 2;
        if (nxt < 22)       { stageA(ph & 1, nxt); stageB(ph & 1, nxt); }
        else if (nxt == 22) { stageTailA(ph & 1);  stageB(ph & 1, 22);  }
    }
    // phases 21, 22: single drain
    asm volatile("s_waitcnt vmcnt(0) lgkmcnt(0)" ::: "memory");
    __builtin_amdgcn_sched_barrier(0);
    __builtin_amdgcn_s_barrier();
    compute(1);                            // phase 21 (buf1)
    compute(0);                            // phase 22 (buf0, tail)

    // epilogue: h1 write + fused attention coefficients (reduce over 8 channels)
    const int wrow0 = brow0 + wave * 16;
    #pragma unroll
    for (int t = 0; t < 4; ++t) {
        const int head = t * 2 + (l16 >> 3);
        const int ch   = l16 & 7;
        const float asc = att_src1[head * 8 + ch];
        const float adc = att_dst1[head * 8 + ch];
        #pragma unroll
        for (int j = 0; j < 4; ++j) {
            int r = wrow0 + l4 * 4 + j;    // C: col = lane&15, row = (lane>>4)*4 + reg
            float ps = acc[t][j] * asc, pd = acc[t][j] * adc;
            ps += __shfl_xor(ps, 1); ps += __shfl_xor(ps, 2); ps += __shfl_xor(ps, 4);
            pd += __shfl_xor(pd, 1); pd += __shfl_xor(pd, 2); pd += __shfl_xor(pd, 4);
            if (r < N_NODES) {
                h1[(size_t)r * 64 + t * 16 + l16] = (_Float16)acc[t][j];
                if (ch == 0) {
                    a_s1[r * 8 + head] = ps;
                    a_d1[r * 8 + head] = pd;
                }
            }
        }
    }
}

// ---------------- layer-1 aggregate (defer-max, 8-deep gather batching) ----------------
__global__ __launch_bounds__(256) void k_agg1(
    const int* __restrict__ offsets, const int* __restrict__ counts,
    const int* __restrict__ sorted_src,
    const float* __restrict__ a_s1, const float* __restrict__ a_d1,
    const _Float16* __restrict__ h1, const float* __restrict__ b1,
    const float* __restrict__ w2, const float* __restrict__ att_src2,
    const float* __restrict__ att_dst2,
    _Float16* __restrict__ g, float* __restrict__ a_s2, float* __restrict__ a_d2) {
    const int lane = threadIdx.x & 63;
    const int wave = threadIdx.x >> 6;
    const int h    = lane & 7;
    const int es   = lane >> 3;
    const int n    = blockIdx.x * 4 + wave;     // 25000*4 = 100000 exact
    const int start = offsets[n];
    const int cnt   = counts[n];
    const float adn = a_d1[n * 8 + h];
    float et = a_s1[n * 8 + h] + adn;
    const float e_self = et > 0.f ? et : 0.2f * et;

    float m = e_self, denom = 0.f;
    float acc[8] = {0.f,0.f,0.f,0.f,0.f,0.f,0.f,0.f};
    if (es == 0) {                 // self-loop: exp(e_self - m) = 1
        denom = 1.f;
        f16x8 hv0 = *(const f16x8*)(h1 + (size_t)n * 64 + h * 8);
        #pragma unroll
        for (int c = 0; c < 8; ++c) acc[c] = (float)hv0[c];
    }
    for (int i = es; i < cnt; i += 64) {
        int   sx[8];
        float ax[8];
        f16x8 vx[8];
        bool  bx[8];
        #pragma unroll
        for (int u = 0; u < 8; ++u) {
            int iu = i + u * 8;
            bx[u] = iu < cnt;
            sx[u] = sorted_src[start + (bx[u] ? iu : i)];
        }
        #pragma unroll
        for (int u = 0; u < 8; ++u) ax[u] = a_s1[sx[u] * 8 + h];
        #pragma unroll
        for (int u = 0; u < 8; ++u) vx[u] = *(const f16x8*)(h1 + (size_t)sx[u] * 64 + h * 8);
        #pragma unroll
        for (int u = 0; u < 8; ++u) {
            if (bx[u]) {
                float e = ax[u] + adn; e = e > 0.f ? e : 0.2f * e;
                if (e > m + 8.f) {     // rare rescale
                    float sc = __expf(m - e); denom *= sc;
                    #pragma unroll
                    for (int c = 0; c < 8; ++c) acc[c] *= sc;
                    m = e;
                }
                float p = __expf(e - m); denom += p;
                #pragma unroll
                for (int c = 0; c < 8; ++c) acc[c] += p * (float)vx[u][c];
            }
        }
    }
    // combine 8 edge-slots per head (xor 8,16,32); m may differ after rescales
    #pragma unroll
    for (int d = 8; d < 64; d <<= 1) {
        float mo = __shfl_xor(m, d);
        float dn = __shfl_xor(denom, d);
        float mn = fmaxf(m, mo);
        float sa = __expf(m - mn), sb = __expf(mo - mn);
        denom = denom * sa + dn * sb;
        #pragma unroll
        for (int c = 0; c < 8; ++c) {
            float ao = __shfl_xor(acc[c], d);
            acc[c] = acc[c] * sa + ao * sb;
        }
        m = mn;
    }
    float inv = 1.f / (denom + 1e-16f);
    float hc[8];
    #pragma unroll
    for (int c = 0; c < 8; ++c) {
        float v = acc[c] * inv;
        v += __shfl_xor(v, 1);
        v += __shfl_xor(v, 2);
        v += __shfl_xor(v, 4);                  // mean over heads
        float o = 0.125f * v + b1[c];
        hc[c] = o > 0.f ? o : expm1f(o);        // ELU
    }
    if (lane == 0) {
        float s2 = 0.f, d2 = 0.f;
        f16x8 gr;
        #pragma unroll
        for (int j = 0; j < 7; ++j) {
            float t = 0.f;
            #pragma unroll
            for (int c = 0; c < 8; ++c) t += hc[c] * w2[c * 7 + j];
            gr[j] = (_Float16)t;
            s2 += t * att_src2[j];
            d2 += t * att_dst2[j];
        }
        gr[7] = (_Float16)0.f;
        *(f16x8*)(g + (size_t)n * 8) = gr;
        a_s2[n] = s2;
        a_d2[n] = d2;
    }
}

// ---------------- layer-2 aggregate (defer-max, 8-deep batching) + log_softmax ----------------
__global__ __launch_bounds__(256) void k_agg2(
    const int* __restrict__ offsets, const int* __restrict__ counts,
    const int* __restrict__ sorted_src,
    const float* __restrict__ a_s2, const float* __restrict__ a_d2,
    const _Float16* __restrict__ g, const float* __restrict__ b2,
    float* __restrict__ outp) {
    const int tid  = threadIdx.x;
    const int lane = tid & 63;
    const int wave = tid >> 6;
    const int grp  = lane >> 3;
    const int s    = lane & 7;
    const int n    = blockIdx.x * 32 + wave * 8 + grp;
    const int start = offsets[n];
    const int cnt   = counts[n];
    const float adn = a_d2[n];
    float et = a_s2[n] + adn;
    const float e_self = et > 0.f ? et : 0.2f * et;

    float m = e_self, denom = 0.f;
    float acc[8] = {0.f,0.f,0.f,0.f,0.f,0.f,0.f,0.f};
    if (s == 0) {
        denom = 1.f;
        f16x8 gv0 = *(const f16x8*)(g + (size_t)n * 8);
        #pragma unroll
        for (int c = 0; c < 8; ++c) acc[c] = (float)gv0[c];
    }
    for (int i = s; i < cnt; i += 64) {
        int   sx[8];
        float ax[8];
        f16x8 vx[8];
        bool  bx[8];
        #pragma unroll
        for (int u = 0; u < 8; ++u) {
            int iu = i + u * 8;
            bx[u] = iu < cnt;
            sx[u] = sorted_src[start + (bx[u] ? iu : i)];
        }
        #pragma unroll
        for (int u = 0; u < 8; ++u) ax[u] = a_s2[sx[u]];
        #pragma unroll
        for (int u = 0; u < 8; ++u) vx[u] = *(const f16x8*)(g + (size_t)sx[u] * 8);
        #pragma unroll
        for (int u = 0; u < 8; ++u) {
            if (bx[u]) {
                float e = ax[u] + adn; e = e > 0.f ? e : 0.2f * e;
                if (e > m + 8.f) {
                    float sc = __expf(m - e); denom *= sc;
                    #pragma unroll
                    for (int c = 0; c < 8; ++c) acc[c] *= sc;
                    m = e;
                }
                float p = __expf(e - m); denom += p;
                #pragma unroll
                for (int c = 0; c < 8; ++c) acc[c] += p * (float)vx[u][c];
            }
        }
    }
    #pragma unroll
    for (int d = 1; d < 8; d <<= 1) {
        float mo = __shfl_xor(m, d, 8);
        float dn = __shfl_xor(denom, d, 8);
        float mn = fmaxf(m, mo);
        float sa = __expf(m - mn), sb = __expf(mo - mn);
        denom = denom * sa + dn * sb;
        #pragma unroll
        for (int c = 0; c < 8; ++c) {
            float ao = __shfl_xor(acc[c], d, 8);
            acc[c] = acc[c] * sa + ao * sb;
        }
        m = mn;
    }
    float inv = 1.f / (denom + 1e-16f);
    float o[7]; float mx = -1e30f;
    #pragma unroll
    for (int c = 0; c < 7; ++c) { o[c] = acc[c] * inv + b2[c]; mx = fmaxf(mx, o[c]); }
    float se = 0.f;
    #pragma unroll
    for (int c = 0; c < 7; ++c) se += __expf(o[c] - mx);
    float ls = mx + logf(se);
    if (s < 7) outp[n * 7 + s] = o[s] - ls;
}

extern "C" void kernel_launch(void* const* d_in, const int* in_sizes, int n_in,
                              void* d_out, int out_size, void* d_ws, size_t ws_size,
                              hipStream_t stream) {
    const float* x        = (const float*)d_in[0];
    const int*   ei       = (const int*)d_in[1];
    const float* W1       = (const float*)d_in[2];
    const float* att_src1 = (const float*)d_in[3];
    const float* att_dst1 = (const float*)d_in[4];
    const float* b1       = (const float*)d_in[5];
    const float* W2       = (const float*)d_in[6];
    const float* att_src2 = (const float*)d_in[7];
    const float* att_dst2 = (const float*)d_in[8];
    const float* b2       = (const float*)d_in[9];
    const int* src = ei;
    const int* dst = ei + E_EDGES;

    char* ws = (char*)d_ws;
    size_t off = 0;
    auto alloc = [&](size_t bytes) -> char* {
        char* p = ws + off;
        off = (off + bytes + 255) & ~(size_t)255;
        return p;
    };
    _Float16* h1         = (_Float16*)alloc((size_t)N_NODES * 64 * 2);
    float*    a_s1       = (float*)   alloc((size_t)N_NODES * 8 * 4);
    float*    a_d1       = (float*)   alloc((size_t)N_NODES * 8 * 4);
    _Float16* w1t        = (_Float16*)alloc((size_t)64 * K_PAD * 2);
    int*      counts     = (int*)     alloc((size_t)N_NODES * 4);
    int*      offsets    = (int*)     alloc((size_t)N_NODES * 4);
    int*      cursor     = (int*)     alloc((size_t)N_NODES * 4);
    int*      csum       = (int*)     alloc((size_t)NCH * 4);
    int*      sorted_src = (int*)     alloc((size_t)(E_EDGES + 32) * 4);
    _Float16* gbuf       = (_Float16*)alloc((size_t)N_NODES * 8 * 2);
    float*    a_s2       = (float*)   alloc((size_t)N_NODES * 4);
    float*    a_d2       = (float*)   alloc((size_t)N_NODES * 4);
    float*    outp       = (float*)d_out;

    hipLaunchKernelGGL(k_init,    dim3(391),   dim3(256), 0, stream, W1, w1t, counts);
    hipLaunchKernelGGL(k_hist,    dim3(3125),  dim3(256), 0, stream, dst, counts);
    hipLaunchKernelGGL(k_scan_a,  dim3(NCH),   dim3(256), 0, stream, counts, csum);
    hipLaunchKernelGGL(k_scan_b,  dim3(1),     dim3(128), 0, stream, csum);
    hipLaunchKernelGGL(k_scan_c,  dim3(NCH),   dim3(256), 0, stream, counts, csum, offsets, cursor);
    hipLaunchKernelGGL(k_scatter, dim3(1563),  dim3(256), 0, stream, src, dst, cursor, sorted_src);
    hipLaunchKernelGGL(k_gemm1,   dim3(1563),  dim3(256), 0, stream, x, w1t, att_src1, att_dst1,
                       h1, a_s1, a_d1);
    hipLaunchKernelGGL(k_agg1,    dim3(25000), dim3(256), 0, stream, offsets, counts, sorted_src,
                       a_s1, a_d1, h1, b1, W2, att_src2, att_dst2, gbuf, a_s2, a_d2);
    hipLaunchKernelGGL(k_agg2,    dim3(3125),  dim3(256), 0, stream, offsets, counts, sorted_src,
                       a_s2, a_d2, gbuf, b2, outp);
}

// Round 19
// 536.190 us; speedup vs baseline: 1.1618x; 1.1090x over previous
//
#include <hip/hip_runtime.h>

#define N_NODES 100000
#define E_EDGES 3200000
#define F_IN    1433
#define K_PAD   1472   // w1t padded K (23*64)
#define NCH     98     // scan chunks of 1024
#define KPH     64     // k per phase; 22 DMA phases + guarded tail

typedef _Float16 f16x4 __attribute__((ext_vector_type(4)));
typedef _Float16 f16x8 __attribute__((ext_vector_type(8)));
typedef float    f32x4 __attribute__((ext_vector_type(4)));

__device__ __forceinline__ void gload_lds16(const void* g, void* l) {
    __builtin_amdgcn_global_load_lds(
        (const __attribute__((address_space(1))) unsigned int*)g,
        (__attribute__((address_space(3))) unsigned int*)l, 16, 0, 0);
}

// ---------------- fused init+hist: blocks [0,368) build w1t, [368,3493) histogram ----------------
// counts is zeroed by hipMemsetAsync before this kernel; w1t and counts/dst are
// disjoint buffers so the two roles need no ordering between them.
__global__ void k_init_hist(const float* __restrict__ w1, _Float16* __restrict__ w1t,
                            const int* __restrict__ dst, int* __restrict__ counts) {
    if (blockIdx.x < 368) {
        int i = blockIdx.x * 256 + threadIdx.x;      // 368*256 = 94208 = 64*K_PAD exact
        int n = i / K_PAD, k = i - n * K_PAD;
        float v = (k < F_IN) ? w1[(size_t)k * 64 + n] : 0.f;
        w1t[i] = (_Float16)v;
        return;
    }
    int idx = (blockIdx.x - 368) * 256 + threadIdx.x;   // 3125*256*4 = 3.2M
    int4 d4 = ((const int4*)dst)[idx];
    atomicAdd(&counts[d4.x], 1);
    atomicAdd(&counts[d4.y], 1);
    atomicAdd(&counts[d4.z], 1);
    atomicAdd(&counts[d4.w], 1);
}

// ---------------- exclusive scan of counts (chunked) ----------------
__global__ void k_scan_a(const int* __restrict__ counts, int* __restrict__ csum) {
    __shared__ int sh[256];
    int b = blockIdx.x, t = threadIdx.x;
    int s = 0;
    for (int j = 0; j < 4; ++j) {
        int idx = b * 1024 + j * 256 + t;
        if (idx < N_NODES) s += counts[idx];
    }
    sh[t] = s; __syncthreads();
    for (int off = 128; off > 0; off >>= 1) {
        if (t < off) sh[t] += sh[t + off];
        __syncthreads();
    }
    if (t == 0) csum[b] = sh[0];
}

__global__ void k_scan_b(int* __restrict__ csum) {
    __shared__ int sh[128];
    int t = threadIdx.x;
    int v = (t < NCH) ? csum[t] : 0;
    sh[t] = v; __syncthreads();
    for (int off = 1; off < 128; off <<= 1) {
        int u = (t >= off) ? sh[t - off] : 0;
        __syncthreads();
        sh[t] += u;
        __syncthreads();
    }
    if (t < NCH) csum[t] = sh[t] - v;   // exclusive
}

__global__ void k_scan_c(const int* __restrict__ counts, const int* __restrict__ csum,
                         int* __restrict__ offsets, int* __restrict__ cursor) {
    __shared__ int sh[256];
    int b = blockIdx.x, t = threadIdx.x;
    int base = b * 1024 + t * 4;
    int c0 = (base + 0 < N_NODES) ? counts[base + 0] : 0;
    int c1 = (base + 1 < N_NODES) ? counts[base + 1] : 0;
    int c2 = (base + 2 < N_NODES) ? counts[base + 2] : 0;
    int c3 = (base + 3 < N_NODES) ? counts[base + 3] : 0;
    int tot = c0 + c1 + c2 + c3;
    sh[t] = tot; __syncthreads();
    for (int off = 1; off < 256; off <<= 1) {
        int v = (t >= off) ? sh[t - off] : 0;
        __syncthreads();
        sh[t] += v;
        __syncthreads();
    }
    int excl = sh[t] - tot;
    int o = csum[b] + excl;
    if (base + 0 < N_NODES) { offsets[base + 0] = o;            cursor[base + 0] = o; }
    if (base + 1 < N_NODES) { int q = o + c0;      offsets[base + 1] = q; cursor[base + 1] = q; }
    if (base + 2 < N_NODES) { int q = o + c0 + c1; offsets[base + 2] = q; cursor[base + 2] = q; }
    if (base + 3 < N_NODES) { int q = o + c0 + c1 + c2; offsets[base + 3] = q; cursor[base + 3] = q; }
}

// ---------------- FUSED: even blocks = gemm1(+att1), odd blocks = scatter ----------------
// (r14 structure, verified best 535us). Scatter sweep-localized; gemm 2-deep counted-vmcnt.
__global__ __launch_bounds__(256) void k_gemm_scat(const float* __restrict__ x,
                                                   const _Float16* __restrict__ w1t,
                                                   const float* __restrict__ att_src1,
                                                   const float* __restrict__ att_dst1,
                                                   _Float16* __restrict__ h1,
                                                   float* __restrict__ a_s1,
                                                   float* __restrict__ a_d1,
                                                   const int* __restrict__ src,
                                                   const int* __restrict__ dst,
                                                   int* __restrict__ cursor,
                                                   int* __restrict__ sorted_src) {
    __shared__ __align__(16) char AsB[2][64 * 256];   // 16 KB per buffer (fp32)
    __shared__ __align__(16) char BsB[2][64 * 128];   //  8 KB per buffer (fp16)
    const int tid = threadIdx.x;

    if (blockIdx.x & 1) {
        // ---------------- scatter role: 2048 edges per block, 7 dst-range sweeps ----------------
        const int sid = blockIdx.x >> 1;
        for (int sweep = 0; sweep < 7; ++sweep) {     // dst>>14: 0..6 for dst<100000
            #pragma unroll
            for (int rep = 0; rep < 2; ++rep) {
                int i4 = sid * 512 + rep * 256 + tid;
                if (i4 < E_EDGES / 4) {
                    int4 s4 = ((const int4*)src)[i4];
                    int4 d4 = ((const int4*)dst)[i4];
                    int p;
                    if ((d4.x >> 14) == sweep) { p = atomicAdd(&cursor[d4.x], 1); sorted_src[p] = s4.x; }
                    if ((d4.y >> 14) == sweep) { p = atomicAdd(&cursor[d4.y], 1); sorted_src[p] = s4.y; }
                    if ((d4.z >> 14) == sweep) { p = atomicAdd(&cursor[d4.z], 1); sorted_src[p] = s4.z; }
                    if ((d4.w >> 14) == sweep) { p = atomicAdd(&cursor[d4.w], 1); sorted_src[p] = s4.w; }
                }
            }
        }
        return;
    }

    // ---------------- gemm1 role (verified r13/r14) ----------------
    const int gid  = blockIdx.x >> 1;
    const int lane = tid & 63;
    const int wave = tid >> 6;
    const int l16  = lane & 15;
    const int l4   = lane >> 4;
    const int brow0 = gid * 64;

    f32x4 acc[4] = {};

    auto stageA = [&](int buf, int ph) {
        #pragma unroll
        for (int j = 0; j < 4; ++j) {
            int p = j * 256 + tid;
            int row = p >> 4, q = p & 15;
            int qs = q ^ (row & 7);
            int grow = brow0 + row; if (grow > N_NODES - 1) grow = N_NODES - 1;
            const float* gp = x + (size_t)grow * F_IN + ph * KPH + qs * 4;
            gload_lds16(gp, AsB[buf] + j * 4096 + wave * 1024);
        }
    };
    auto stageB = [&](int buf, int ph) {
        #pragma unroll
        for (int j = 0; j < 2; ++j) {
            int p = j * 256 + tid;
            int col = p >> 3, c = p & 7;
            int cs = c ^ (col & 7);
            const _Float16* gp = w1t + (size_t)col * K_PAD + ph * KPH + cs * 8;
            gload_lds16(gp, BsB[buf] + j * 4096 + wave * 1024);
        }
    };
    auto stageTailA = [&](int buf) {        // k 1408..1471, zero-fill k>=1433
        for (int i = tid; i < 1024; i += 256) {
            int row = i >> 4, q = i & 15;
            int qs = q ^ (row & 7);
            int grow = brow0 + row; if (grow > N_NODES - 1) grow = N_NODES - 1;
            const float* gp = x + (size_t)grow * F_IN;
            float4 v;
            #pragma unroll
            for (int jj = 0; jj < 4; ++jj) {
                int k = 1408 + qs * 4 + jj;
                ((float*)&v)[jj] = (k < F_IN) ? gp[k] : 0.f;
            }
            *(float4*)(AsB[buf] + row * 256 + q * 16) = v;
        }
    };
    auto compute = [&](int buf) {
        const int rA = wave * 16 + l16;
        const char* Ab = AsB[buf] + rA * 256;
        const int r7 = rA & 7;
        #pragma unroll
        for (int st = 0; st < 4; ++st) {
            float4 af = *(const float4*)(Ab + ((((st << 2) + l4) ^ r7) << 4));
            f16x4 a = { (_Float16)af.x, (_Float16)af.y, (_Float16)af.z, (_Float16)af.w };
            #pragma unroll
            for (int t = 0; t < 4; ++t) {
                const int cB = t * 16 + l16;
                const int chunk = (st << 1) + (l4 >> 1);
                const int boff = cB * 128 + ((chunk ^ (cB & 7)) << 4) + ((l4 & 1) << 3);
                f16x4 b = *(const f16x4*)(BsB[buf] + boff);
                acc[t] = __builtin_amdgcn_mfma_f32_16x16x16f16(a, b, acc[t], 0, 0, 0);
            }
        }
    };

    // prologue: stage phases 0 and 1 (12 DMAs in flight per wave)
    stageA(0, 0); stageB(0, 0);
    stageA(1, 1); stageB(1, 1);
    // steady state: compute(ph) from buf[ph&1]; stage(ph+2) into the freed buffer
    for (int ph = 0; ph <= 20; ++ph) {
        asm volatile("s_waitcnt vmcnt(6)" ::: "memory");   // buf[ph&1]'s 6 DMAs done
        __builtin_amdgcn_sched_barrier(0);
        __builtin_amdgcn_s_barrier();                      // all waves agree
        compute(ph & 1);
        asm volatile("s_waitcnt lgkmcnt(0)" ::: "memory"); // reads retired before overwrite
        __builtin_amdgcn_s_barrier();
        int nxt = ph + 2;
        if (nxt < 22)       { stageA(ph & 1, nxt); stageB(ph & 1, nxt); }
        else if (nxt == 22) { stageTailA(ph & 1);  stageB(ph & 1, 22);  }
    }
    // phases 21, 22: single drain
    asm volatile("s_waitcnt vmcnt(0) lgkmcnt(0)" ::: "memory");
    __builtin_amdgcn_sched_barrier(0);
    __builtin_amdgcn_s_barrier();
    compute(1);                            // phase 21 (buf1)
    compute(0);                            // phase 22 (buf0, tail)

    // epilogue: h1 write + fused attention coefficients (reduce over 8 channels)
    const int wrow0 = brow0 + wave * 16;
    #pragma unroll
    for (int t = 0; t < 4; ++t) {
        const int head = t * 2 + (l16 >> 3);
        const int ch   = l16 & 7;
        const float asc = att_src1[head * 8 + ch];
        const float adc = att_dst1[head * 8 + ch];
        #pragma unroll
        for (int j = 0; j < 4; ++j) {
            int r = wrow0 + l4 * 4 + j;    // C: col = lane&15, row = (lane>>4)*4 + reg
            float ps = acc[t][j] * asc, pd = acc[t][j] * adc;
            ps += __shfl_xor(ps, 1); ps += __shfl_xor(ps, 2); ps += __shfl_xor(ps, 4);
            pd += __shfl_xor(pd, 1); pd += __shfl_xor(pd, 2); pd += __shfl_xor(pd, 4);
            if (r < N_NODES) {
                h1[(size_t)r * 64 + t * 16 + l16] = (_Float16)acc[t][j];
                if (ch == 0) {
                    a_s1[r * 8 + head] = ps;
                    a_d1[r * 8 + head] = pd;
                }
            }
        }
    }
}

// ---------------- layer-1 aggregate (defer-max, 4-deep gather batching) ----------------
__global__ __launch_bounds__(256) void k_agg1(
    const int* __restrict__ offsets, const int* __restrict__ counts,
    const int* __restrict__ sorted_src,
    const float* __restrict__ a_s1, const float* __restrict__ a_d1,
    const _Float16* __restrict__ h1, const float* __restrict__ b1,
    const float* __restrict__ w2, const float* __restrict__ att_src2,
    const float* __restrict__ att_dst2,
    _Float16* __restrict__ g, float* __restrict__ a_s2, float* __restrict__ a_d2) {
    const int lane = threadIdx.x & 63;
    const int wave = threadIdx.x >> 6;
    const int h    = lane & 7;
    const int es   = lane >> 3;
    const int n    = blockIdx.x * 4 + wave;     // 25000*4 = 100000 exact
    const int start = offsets[n];
    const int cnt   = counts[n];
    const float adn = a_d1[n * 8 + h];
    float et = a_s1[n * 8 + h] + adn;
    const float e_self = et > 0.f ? et : 0.2f * et;

    float m = e_self, denom = 0.f;
    float acc[8] = {0.f,0.f,0.f,0.f,0.f,0.f,0.f,0.f};
    if (es == 0) {                 // self-loop: exp(e_self - m) = 1
        denom = 1.f;
        f16x8 hv0 = *(const f16x8*)(h1 + (size_t)n * 64 + h * 8);
        #pragma unroll
        for (int c = 0; c < 8; ++c) acc[c] = (float)hv0[c];
    }
    for (int i = es; i < cnt; i += 32) {
        const int i1 = i + 8, i2 = i + 16, i3 = i + 24;
        const bool b1v = i1 < cnt, b2v = i2 < cnt, b3v = i3 < cnt;
        int s0 = sorted_src[start + i];
        int s1 = sorted_src[start + (b1v ? i1 : i)];
        int s2 = sorted_src[start + (b2v ? i2 : i)];
        int s3 = sorted_src[start + (b3v ? i3 : i)];
        float a0 = a_s1[s0 * 8 + h];
        float a1 = a_s1[s1 * 8 + h];
        float a2 = a_s1[s2 * 8 + h];
        float a3 = a_s1[s3 * 8 + h];
        f16x8 v0 = *(const f16x8*)(h1 + (size_t)s0 * 64 + h * 8);
        f16x8 v1 = *(const f16x8*)(h1 + (size_t)s1 * 64 + h * 8);
        f16x8 v2 = *(const f16x8*)(h1 + (size_t)s2 * 64 + h * 8);
        f16x8 v3 = *(const f16x8*)(h1 + (size_t)s3 * 64 + h * 8);
        {
            float e = a0 + adn; e = e > 0.f ? e : 0.2f * e;
            if (e > m + 8.f) { float sc = __expf(m - e); denom *= sc;
                #pragma unroll
                for (int c = 0; c < 8; ++c) acc[c] *= sc; m = e; }
            float p = __expf(e - m); denom += p;
            #pragma unroll
            for (int c = 0; c < 8; ++c) acc[c] += p * (float)v0[c];
        }
        if (b1v) {
            float e = a1 + adn; e = e > 0.f ? e : 0.2f * e;
            if (e > m + 8.f) { float sc = __expf(m - e); denom *= sc;
                #pragma unroll
                for (int c = 0; c < 8; ++c) acc[c] *= sc; m = e; }
            float p = __expf(e - m); denom += p;
            #pragma unroll
            for (int c = 0; c < 8; ++c) acc[c] += p * (float)v1[c];
        }
        if (b2v) {
            float e = a2 + adn; e = e > 0.f ? e : 0.2f * e;
            if (e > m + 8.f) { float sc = __expf(m - e); denom *= sc;
                #pragma unroll
                for (int c = 0; c < 8; ++c) acc[c] *= sc; m = e; }
            float p = __expf(e - m); denom += p;
            #pragma unroll
            for (int c = 0; c < 8; ++c) acc[c] += p * (float)v2[c];
        }
        if (b3v) {
            float e = a3 + adn; e = e > 0.f ? e : 0.2f * e;
            if (e > m + 8.f) { float sc = __expf(m - e); denom *= sc;
                #pragma unroll
                for (int c = 0; c < 8; ++c) acc[c] *= sc; m = e; }
            float p = __expf(e - m); denom += p;
            #pragma unroll
            for (int c = 0; c < 8; ++c) acc[c] += p * (float)v3[c];
        }
    }
    // combine 8 edge-slots per head (xor 8,16,32); m may differ after rescales
    #pragma unroll
    for (int d = 8; d < 64; d <<= 1) {
        float mo = __shfl_xor(m, d);
        float dn = __shfl_xor(denom, d);
        float mn = fmaxf(m, mo);
        float sa = __expf(m - mn), sb = __expf(mo - mn);
        denom = denom * sa + dn * sb;
        #pragma unroll
        for (int c = 0; c < 8; ++c) {
            float ao = __shfl_xor(acc[c], d);
            acc[c] = acc[c] * sa + ao * sb;
        }
        m = mn;
    }
    float inv = 1.f / (denom + 1e-16f);
    float hc[8];
    #pragma unroll
    for (int c = 0; c < 8; ++c) {
        float v = acc[c] * inv;
        v += __shfl_xor(v, 1);
        v += __shfl_xor(v, 2);
        v += __shfl_xor(v, 4);                  // mean over heads
        float o = 0.125f * v + b1[c];
        hc[c] = o > 0.f ? o : expm1f(o);        // ELU
    }
    if (lane == 0) {
        float s2 = 0.f, d2 = 0.f;
        f16x8 gr;
        #pragma unroll
        for (int j = 0; j < 7; ++j) {
            float t = 0.f;
            #pragma unroll
            for (int c = 0; c < 8; ++c) t += hc[c] * w2[c * 7 + j];
            gr[j] = (_Float16)t;
            s2 += t * att_src2[j];
            d2 += t * att_dst2[j];
        }
        gr[7] = (_Float16)0.f;
        *(f16x8*)(g + (size_t)n * 8) = gr;
        a_s2[n] = s2;
        a_d2[n] = d2;
    }
}

// ---------------- layer-2 aggregate (defer-max, 4-deep batching) + log_softmax ----------------
__global__ __launch_bounds__(256) void k_agg2(
    const int* __restrict__ offsets, const int* __restrict__ counts,
    const int* __restrict__ sorted_src,
    const float* __restrict__ a_s2, const float* __restrict__ a_d2,
    const _Float16* __restrict__ g, const float* __restrict__ b2,
    float* __restrict__ outp) {
    const int tid  = threadIdx.x;
    const int lane = tid & 63;
    const int wave = tid >> 6;
    const int grp  = lane >> 3;
    const int s    = lane & 7;
    const int n    = blockIdx.x * 32 + wave * 8 + grp;
    const int start = offsets[n];
    const int cnt   = counts[n];
    const float adn = a_d2[n];
    float et = a_s2[n] + adn;
    const float e_self = et > 0.f ? et : 0.2f * et;

    float m = e_self, denom = 0.f;
    float acc[8] = {0.f,0.f,0.f,0.f,0.f,0.f,0.f,0.f};
    if (s == 0) {
        denom = 1.f;
        f16x8 gv0 = *(const f16x8*)(g + (size_t)n * 8);
        #pragma unroll
        for (int c = 0; c < 8; ++c) acc[c] = (float)gv0[c];
    }
    for (int i = s; i < cnt; i += 32) {
        const int i1 = i + 8, i2 = i + 16, i3 = i + 24;
        const bool b1v = i1 < cnt, b2v = i2 < cnt, b3v = i3 < cnt;
        int s0 = sorted_src[start + i];
        int s1 = sorted_src[start + (b1v ? i1 : i)];
        int s2 = sorted_src[start + (b2v ? i2 : i)];
        int s3 = sorted_src[start + (b3v ? i3 : i)];
        float a0 = a_s2[s0], a1 = a_s2[s1], a2 = a_s2[s2], a3 = a_s2[s3];
        f16x8 v0 = *(const f16x8*)(g + (size_t)s0 * 8);
        f16x8 v1 = *(const f16x8*)(g + (size_t)s1 * 8);
        f16x8 v2 = *(const f16x8*)(g + (size_t)s2 * 8);
        f16x8 v3 = *(const f16x8*)(g + (size_t)s3 * 8);
        {
            float e = a0 + adn; e = e > 0.f ? e : 0.2f * e;
            if (e > m + 8.f) { float sc = __expf(m - e); denom *= sc;
                #pragma unroll
                for (int c = 0; c < 8; ++c) acc[c] *= sc; m = e; }
            float p = __expf(e - m); denom += p;
            #pragma unroll
            for (int c = 0; c < 8; ++c) acc[c] += p * (float)v0[c];
        }
        if (b1v) {
            float e = a1 + adn; e = e > 0.f ? e : 0.2f * e;
            if (e > m + 8.f) { float sc = __expf(m - e); denom *= sc;
                #pragma unroll
                for (int c = 0; c < 8; ++c) acc[c] *= sc; m = e; }
            float p = __expf(e - m); denom += p;
            #pragma unroll
            for (int c = 0; c < 8; ++c) acc[c] += p * (float)v1[c];
        }
        if (b2v) {
            float e = a2 + adn; e = e > 0.f ? e : 0.2f * e;
            if (e > m + 8.f) { float sc = __expf(m - e); denom *= sc;
                #pragma unroll
                for (int c = 0; c < 8; ++c) acc[c] *= sc; m = e; }
            float p = __expf(e - m); denom += p;
            #pragma unroll
            for (int c = 0; c < 8; ++c) acc[c] += p * (float)v2[c];
        }
        if (b3v) {
            float e = a3 + adn; e = e > 0.f ? e : 0.2f * e;
            if (e > m + 8.f) { float sc = __expf(m - e); denom *= sc;
                #pragma unroll
                for (int c = 0; c < 8; ++c) acc[c] *= sc; m = e; }
            float p = __expf(e - m); denom += p;
            #pragma unroll
            for (int c = 0; c < 8; ++c) acc[c] += p * (float)v3[c];
        }
    }
    #pragma unroll
    for (int d = 1; d < 8; d <<= 1) {
        float mo = __shfl_xor(m, d, 8);
        float dn = __shfl_xor(denom, d, 8);
        float mn = fmaxf(m, mo);
        float sa = __expf(m - mn), sb = __expf(mo - mn);
        denom = denom * sa + dn * sb;
        #pragma unroll
        for (int c = 0; c < 8; ++c) {
            float ao = __shfl_xor(acc[c], d, 8);
            acc[c] = acc[c] * sa + ao * sb;
        }
        m = mn;
    }
    float inv = 1.f / (denom + 1e-16f);
    float o[7]; float mx = -1e30f;
    #pragma unroll
    for (int c = 0; c < 7; ++c) { o[c] = acc[c] * inv + b2[c]; mx = fmaxf(mx, o[c]); }
    float se = 0.f;
    #pragma unroll
    for (int c = 0; c < 7; ++c) se += __expf(o[c] - mx);
    float ls = mx + logf(se);
    if (s < 7) outp[n * 7 + s] = o[s] - ls;
}

extern "C" void kernel_launch(void* const* d_in, const int* in_sizes, int n_in,
                              void* d_out, int out_size, void* d_ws, size_t ws_size,
                              hipStream_t stream) {
    const float* x        = (const float*)d_in[0];
    const int*   ei       = (const int*)d_in[1];
    const float* W1       = (const float*)d_in[2];
    const float* att_src1 = (const float*)d_in[3];
    const float* att_dst1 = (const float*)d_in[4];
    const float* b1       = (const float*)d_in[5];
    const float* W2       = (const float*)d_in[6];
    const float* att_src2 = (const float*)d_in[7];
    const float* att_dst2 = (const float*)d_in[8];
    const float* b2       = (const float*)d_in[9];
    const int* src = ei;
    const int* dst = ei + E_EDGES;

    char* ws = (char*)d_ws;
    size_t off = 0;
    auto alloc = [&](size_t bytes) -> char* {
        char* p = ws + off;
        off = (off + bytes + 255) & ~(size_t)255;
        return p;
    };
    _Float16* h1         = (_Float16*)alloc((size_t)N_NODES * 64 * 2);
    float*    a_s1       = (float*)   alloc((size_t)N_NODES * 8 * 4);
    float*    a_d1       = (float*)   alloc((size_t)N_NODES * 8 * 4);
    _Float16* w1t        = (_Float16*)alloc((size_t)64 * K_PAD * 2);
    int*      counts     = (int*)     alloc((size_t)N_NODES * 4);
    int*      offsets    = (int*)     alloc((size_t)N_NODES * 4);
    int*      cursor     = (int*)     alloc((size_t)N_NODES * 4);
    int*      csum       = (int*)     alloc((size_t)NCH * 4);
    int*      sorted_src = (int*)     alloc((size_t)(E_EDGES + 32) * 4);
    _Float16* gbuf       = (_Float16*)alloc((size_t)N_NODES * 8 * 2);
    float*    a_s2       = (float*)   alloc((size_t)N_NODES * 4);
    float*    a_d2       = (float*)   alloc((size_t)N_NODES * 4);
    float*    outp       = (float*)d_out;

    hipMemsetAsync(counts, 0, (size_t)N_NODES * 4, stream);
    hipLaunchKernelGGL(k_init_hist, dim3(3493),  dim3(256), 0, stream, W1, w1t, dst, counts);
    hipLaunchKernelGGL(k_scan_a,    dim3(NCH),   dim3(256), 0, stream, counts, csum);
    hipLaunchKernelGGL(k_scan_b,    dim3(1),     dim3(128), 0, stream, csum);
    hipLaunchKernelGGL(k_scan_c,    dim3(NCH),   dim3(256), 0, stream, counts, csum, offsets, cursor);
    hipLaunchKernelGGL(k_gemm_scat, dim3(3126),  dim3(256), 0, stream,
                       x, w1t, att_src1, att_dst1, h1, a_s1, a_d1,
                       src, dst, cursor, sorted_src);
    hipLaunchKernelGGL(k_agg1,      dim3(25000), dim3(256), 0, stream, offsets, counts, sorted_src,
                       a_s1, a_d1, h1, b1, W2, att_src2, att_dst2, gbuf, a_s2, a_d2);
    hipLaunchKernelGGL(k_agg2,      dim3(3125),  dim3(256), 0, stream, offsets, counts, sorted_src,
                       a_s2, a_d2, gbuf, b2, outp);
}